// Round 6
// baseline (117.507 us; speedup 1.0000x reference)
//
#include <hip/hip_runtime.h>

#define HW   262144   // 512*512
#define HW4  65536    // HW/4
#define NSEG 256
#define NB   8

// -------- Kernel 1: counting-sort segment moments ------------------------
// 1024 blocks x 2048 px (8 px/thread), R4-proven geometry. Phase A: 1
// ds_add_rtn_u32 per pixel (rank). Phase B: block scan of 256 bins. Phase C:
// scatter RGB float4 into label-sorted LDS. Phase D: thread t reduces
// segment t's run in registers. Merge: 10 global_atomic_add_f32 per thread
// directly into acc[b][10][256] (replaces the 10.5MB part write + 10.5MB
// k_reduce read -- R4 measured this traffic term at ~4us per 10.5MB saved).
__global__ __launch_bounds__(256) void k_moments(const float* __restrict__ x,
                                                 const int* __restrict__ labels,
                                                 float* __restrict__ acc) {
  __shared__ unsigned cnt[NSEG];
  __shared__ unsigned offs[NSEG];
  __shared__ unsigned wtot[4];
  __shared__ __align__(16) float buf[2048][4];   // 32 KB sorted RGB
  const int t = threadIdx.x, w = t >> 6, lane = t & 63;
  const int b = blockIdx.x >> 7, blk = blockIdx.x & 127;  // 128 blocks/batch

  cnt[t] = 0u;
  __syncthreads();

  const float4* __restrict__ x4 = (const float4*)(x + (size_t)b * 3 * HW);
  const int4*  __restrict__ l4  = (const int4*)(labels + (size_t)b * HW);

  float4 A0[2], A1[2], A2[2];
  int lb[8];
  unsigned rk[8];

  // load 8 pixels/thread (issue all global loads up front)
  #pragma unroll
  for (int it = 0; it < 2; ++it) {
    const int g = blk * 512 + w * 128 + it * 64 + lane;   // float4 idx in channel
    A0[it] = x4[g];
    A1[it] = x4[HW4 + g];
    A2[it] = x4[2 * HW4 + g];
    int4 lv = l4[g];
    lb[it * 4 + 0] = lv.x; lb[it * 4 + 1] = lv.y;
    lb[it * 4 + 2] = lv.z; lb[it * 4 + 3] = lv.w;
  }

  // Phase A: histogram + per-pixel rank (1 rtn-atomic per pixel)
  #pragma unroll
  for (int k = 0; k < 8; ++k) rk[k] = atomicAdd(&cnt[lb[k]], 1u);
  __syncthreads();

  // Phase B: exclusive scan of cnt -> offs (wave shuffle scan + wave offsets)
  const unsigned v = cnt[t];
  unsigned inc = v;
  #pragma unroll
  for (int off = 1; off < 64; off <<= 1) {
    unsigned u = __shfl_up(inc, off, 64);
    if (lane >= off) inc += u;
  }
  if (lane == 63) wtot[w] = inc;
  __syncthreads();
  unsigned wbase = 0;
  #pragma unroll
  for (int i = 0; i < 3; ++i) if (i < w) wbase += wtot[i];
  offs[t] = wbase + inc - v;
  __syncthreads();

  // Phase C: scatter sorted RGB
  #pragma unroll
  for (int it = 0; it < 2; ++it) {
    float c0[4] = {A0[it].x, A0[it].y, A0[it].z, A0[it].w};
    float c1[4] = {A1[it].x, A1[it].y, A1[it].z, A1[it].w};
    float c2[4] = {A2[it].x, A2[it].y, A2[it].z, A2[it].w};
    #pragma unroll
    for (int k = 0; k < 4; ++k) {
      const int p = it * 4 + k;
      const unsigned pos = offs[lb[p]] + rk[p];
      *(float4*)&buf[pos][0] = make_float4(c0[k], c1[k], c2[k], 0.f);
    }
  }
  __syncthreads();

  // Phase D: thread t reduces segment t's run serially (registers only)
  const unsigned n = cnt[t], base = offs[t];
  float s0 = 0.f, s1 = 0.f, s2 = 0.f;
  float q00 = 0.f, q11 = 0.f, q22 = 0.f, q01 = 0.f, q02 = 0.f, q12 = 0.f;
  for (unsigned i = 0; i < n; ++i) {
    float4 p = *(const float4*)&buf[base + i][0];
    s0 += p.x;  s1 += p.y;  s2 += p.z;
    q00 += p.x * p.x;  q11 += p.y * p.y;  q22 += p.z * p.z;
    q01 += p.x * p.y;  q02 += p.x * p.z;  q12 += p.y * p.z;
  }

  // merge directly into acc[b][10][256] (coalesced atomic lines, pre-zeroed)
  float* o = acc + (size_t)b * 2560;
  unsafeAtomicAdd(&o[0 * NSEG + t], (float)n);
  unsafeAtomicAdd(&o[1 * NSEG + t], s0);
  unsafeAtomicAdd(&o[2 * NSEG + t], s1);
  unsafeAtomicAdd(&o[3 * NSEG + t], s2);
  unsafeAtomicAdd(&o[4 * NSEG + t], q00);
  unsafeAtomicAdd(&o[5 * NSEG + t], q11);
  unsafeAtomicAdd(&o[6 * NSEG + t], q22);
  unsafeAtomicAdd(&o[7 * NSEG + t], q01);
  unsafeAtomicAdd(&o[8 * NSEG + t], q02);
  unsafeAtomicAdd(&o[9 * NSEG + t], q12);
}

// -------- Kernel 2: moments -> mean/std -> reduce_conv -> L2 normalize ----
__global__ __launch_bounds__(256) void k_stats(const float* __restrict__ acc,
                                               const float* __restrict__ W_pix,
                                               const float* __restrict__ b_pix,
                                               const float* __restrict__ W_red,
                                               const float* __restrict__ b_red,
                                               float* __restrict__ rn) {
  __shared__ float wred[64 * 129];
  __shared__ float comb[4][132];
  const int t = threadIdx.x;

  for (int j4 = t; j4 < 2048; j4 += 256) {
    const int row = j4 >> 5;
    const int c4  = (j4 & 31) << 2;
    float4 v = ((const float4*)W_red)[j4];
    float* d = &wred[row * 129 + c4];
    d[0] = v.x; d[1] = v.y; d[2] = v.z; d[3] = v.w;
  }
  __syncthreads();

  const int w = t >> 6;
  const int f = t & 63;
  const int seg = blockIdx.x * 4 + w;
  const int b = seg >> 8;
  const int s = seg & 255;

  const float* a = acc + b * (10 * NSEG);
  const float N   = fmaxf(a[0 * NSEG + s], 1.0f);
  const float S0  = a[1 * NSEG + s];
  const float S1  = a[2 * NSEG + s];
  const float S2  = a[3 * NSEG + s];
  const float M00 = a[4 * NSEG + s];
  const float M11 = a[5 * NSEG + s];
  const float M22 = a[6 * NSEG + s];
  const float M01 = a[7 * NSEG + s];
  const float M02 = a[8 * NSEG + s];
  const float M12 = a[9 * NSEG + s];

  const float w0 = W_pix[f * 3 + 0];
  const float w1 = W_pix[f * 3 + 1];
  const float w2 = W_pix[f * 3 + 2];
  const float bf = b_pix[f];

  const float wS   = w0 * S0 + w1 * S1 + w2 * S2;
  const float mean = (wS + N * bf) / N;
  const float ssq  = w0 * w0 * M00 + w1 * w1 * M11 + w2 * w2 * M22
                   + 2.f * (w0 * w1 * M01 + w0 * w2 * M02 + w1 * w2 * M12)
                   + 2.f * bf * wS + N * bf * bf;
  const float var  = ssq / N - mean * mean;
  const float stdv = sqrtf(fmaxf(var, 1e-6f));

  comb[w][f]      = mean;
  comb[w][64 + f] = stdv;
  __syncthreads();

  float r = b_red[f];
  const float* wr = &wred[f * 129];
  const float* cb = comb[w];
  for (int g = 0; g < 128; ++g) r += wr[g] * cb[g];

  float sq = r * r;
  #pragma unroll
  for (int off = 32; off > 0; off >>= 1) sq += __shfl_xor(sq, off, 64);
  const float inv = 1.0f / fmaxf(sqrtf(sq), 1e-12f);

  rn[(size_t)seg * 64 + f] = r * inv;
}

// -------- Kernel 3: sim = rn rn^T, fused conv1x1 + BN(eval) + ReLU --------
__global__ __launch_bounds__(256) void k_sim(const float* __restrict__ rn,
                                             float* __restrict__ out,
                                             const float* __restrict__ w_sim,
                                             const float* __restrict__ b_sim,
                                             const float* __restrict__ bn_g,
                                             const float* __restrict__ bn_b,
                                             const float* __restrict__ bn_m,
                                             const float* __restrict__ bn_v) {
  __shared__ float A[64 * 65];
  __shared__ float Bt[64 * 65];
  const int t  = threadIdx.x;
  const int b  = blockIdx.x >> 4;
  const int ti = (blockIdx.x >> 2) & 3;
  const int tj = blockIdx.x & 3;

  const float4* rn4 = (const float4*)(rn + (size_t)b * NSEG * 64);
  for (int j4 = t; j4 < 1024; j4 += 256) {
    const int row = j4 >> 4;
    const int c4  = (j4 & 15) << 2;
    float4 va = rn4[(ti * 64 + row) * 16 + (j4 & 15)];
    float* da = &A[row * 65 + c4];
    da[0] = va.x; da[1] = va.y; da[2] = va.z; da[3] = va.w;
    float4 vb = rn4[(tj * 64 + row) * 16 + (j4 & 15)];
    float* db = &Bt[row * 65 + c4];
    db[0] = vb.x; db[1] = vb.y; db[2] = vb.z; db[3] = vb.w;
  }
  __syncthreads();

  const int tx = t & 15;
  const int ty = t >> 4;
  float acc[4][4] = {{0.f}};
  for (int k = 0; k < 64; ++k) {
    float av[4], bv[4];
    #pragma unroll
    for (int i = 0; i < 4; ++i) av[i] = A[(ty * 4 + i) * 65 + k];
    #pragma unroll
    for (int j = 0; j < 4; ++j) bv[j] = Bt[(tx * 4 + j) * 65 + k];
    #pragma unroll
    for (int i = 0; i < 4; ++i)
      #pragma unroll
      for (int j = 0; j < 4; ++j) acc[i][j] += av[i] * bv[j];
  }

  const float invsd = 1.0f / sqrtf(bn_v[0] + 1e-5f);
  const float scale = w_sim[0] * bn_g[0] * invsd;
  const float shift = (b_sim[0] - bn_m[0]) * bn_g[0] * invsd + bn_b[0];

  #pragma unroll
  for (int i = 0; i < 4; ++i) {
    float4 v;
    v.x = fmaxf(acc[i][0] * scale + shift, 0.f);
    v.y = fmaxf(acc[i][1] * scale + shift, 0.f);
    v.z = fmaxf(acc[i][2] * scale + shift, 0.f);
    v.w = fmaxf(acc[i][3] * scale + shift, 0.f);
    const int base = b * 65536 + (ti * 64 + ty * 4 + i) * 256 + tj * 64;
    ((float4*)out)[(base >> 2) + tx] = v;
  }
}

extern "C" void kernel_launch(void* const* d_in, const int* in_sizes, int n_in,
                              void* d_out, int out_size, void* d_ws, size_t ws_size,
                              hipStream_t stream) {
  (void)in_sizes; (void)n_in; (void)out_size; (void)ws_size;
  const float* x      = (const float*)d_in[0];
  const int*   labels = (const int*)d_in[1];
  const float* W_pix  = (const float*)d_in[3];
  const float* b_pix  = (const float*)d_in[4];
  const float* W_red  = (const float*)d_in[5];
  const float* b_red  = (const float*)d_in[6];
  const float* w_sim  = (const float*)d_in[7];
  const float* b_sim  = (const float*)d_in[8];
  const float* bn_g   = (const float*)d_in[9];
  const float* bn_b   = (const float*)d_in[10];
  const float* bn_m   = (const float*)d_in[11];
  const float* bn_v   = (const float*)d_in[12];
  float* out = (float*)d_out;

  float* acc = (float*)d_ws;                 // 8*10*256 f32 = 80 KB
  float* rn  = acc + NB * 10 * NSEG;         // 8*256*64 f32 = 512 KB

  hipMemsetAsync(acc, 0, (size_t)NB * 10 * NSEG * sizeof(float), stream);
  k_moments<<<dim3(1024), dim3(256), 0, stream>>>(x, labels, acc);
  k_stats<<<dim3(512), dim3(256), 0, stream>>>(acc, W_pix, b_pix, W_red, b_red, rn);
  k_sim<<<dim3(128), dim3(256), 0, stream>>>(rn, out, w_sim, b_sim, bn_g, bn_b, bn_m, bn_v);
}

// Round 7
// 114.394 us; speedup vs baseline: 1.0272x; 1.0272x over previous
//
#include <hip/hip_runtime.h>

#define HW   262144   // 512*512
#define HW4  65536    // HW/4
#define NSEG 256
#define NB   8

// -------- Kernel 1: counting-sort segment moments ------------------------
// 1024 blocks x 2048 px (8 px/thread). Best-measured configuration (R4,
// 114.7us): explicit part write (10.5MB) + k_reduce beats both the 21MB
// variant (R3 118.6) and the zero-traffic global-atomic merge (R6 117.5).
// Phase A: 1 ds_add_rtn_u32 per pixel (rank). Phase B: block scan of 256
// bins. Phase C: scatter RGB float4 into label-sorted LDS. Phase D: thread t
// reduces segment t's run in registers. Coalesced partial store.
__global__ __launch_bounds__(256) void k_moments(const float* __restrict__ x,
                                                 const int* __restrict__ labels,
                                                 float* __restrict__ part) {
  __shared__ unsigned cnt[NSEG];
  __shared__ unsigned offs[NSEG];
  __shared__ unsigned wtot[4];
  __shared__ __align__(16) float buf[2048][4];   // 32 KB sorted RGB
  const int t = threadIdx.x, w = t >> 6, lane = t & 63;
  const int b = blockIdx.x >> 7, blk = blockIdx.x & 127;  // 128 blocks/batch

  cnt[t] = 0u;
  __syncthreads();

  const float4* __restrict__ x4 = (const float4*)(x + (size_t)b * 3 * HW);
  const int4*  __restrict__ l4  = (const int4*)(labels + (size_t)b * HW);

  float4 A0[2], A1[2], A2[2];
  int lb[8];
  unsigned rk[8];

  // load 8 pixels/thread (issue all global loads up front)
  #pragma unroll
  for (int it = 0; it < 2; ++it) {
    const int g = blk * 512 + w * 128 + it * 64 + lane;   // float4 idx in channel
    A0[it] = x4[g];
    A1[it] = x4[HW4 + g];
    A2[it] = x4[2 * HW4 + g];
    int4 lv = l4[g];
    lb[it * 4 + 0] = lv.x; lb[it * 4 + 1] = lv.y;
    lb[it * 4 + 2] = lv.z; lb[it * 4 + 3] = lv.w;
  }

  // Phase A: histogram + per-pixel rank (1 rtn-atomic per pixel)
  #pragma unroll
  for (int k = 0; k < 8; ++k) rk[k] = atomicAdd(&cnt[lb[k]], 1u);
  __syncthreads();

  // Phase B: exclusive scan of cnt -> offs (wave shuffle scan + wave offsets)
  const unsigned v = cnt[t];
  unsigned inc = v;
  #pragma unroll
  for (int off = 1; off < 64; off <<= 1) {
    unsigned u = __shfl_up(inc, off, 64);
    if (lane >= off) inc += u;
  }
  if (lane == 63) wtot[w] = inc;
  __syncthreads();
  unsigned wbase = 0;
  #pragma unroll
  for (int i = 0; i < 3; ++i) if (i < w) wbase += wtot[i];
  offs[t] = wbase + inc - v;
  __syncthreads();

  // Phase C: scatter sorted RGB
  #pragma unroll
  for (int it = 0; it < 2; ++it) {
    float c0[4] = {A0[it].x, A0[it].y, A0[it].z, A0[it].w};
    float c1[4] = {A1[it].x, A1[it].y, A1[it].z, A1[it].w};
    float c2[4] = {A2[it].x, A2[it].y, A2[it].z, A2[it].w};
    #pragma unroll
    for (int k = 0; k < 4; ++k) {
      const int p = it * 4 + k;
      const unsigned pos = offs[lb[p]] + rk[p];
      *(float4*)&buf[pos][0] = make_float4(c0[k], c1[k], c2[k], 0.f);
    }
  }
  __syncthreads();

  // Phase D: thread t reduces segment t's run serially (registers only)
  const unsigned n = cnt[t], base = offs[t];
  float s0 = 0.f, s1 = 0.f, s2 = 0.f;
  float q00 = 0.f, q11 = 0.f, q22 = 0.f, q01 = 0.f, q02 = 0.f, q12 = 0.f;
  for (unsigned i = 0; i < n; ++i) {
    float4 p = *(const float4*)&buf[base + i][0];
    s0 += p.x;  s1 += p.y;  s2 += p.z;
    q00 += p.x * p.x;  q11 += p.y * p.y;  q22 += p.z * p.z;
    q01 += p.x * p.y;  q02 += p.x * p.z;  q12 += p.y * p.z;
  }

  float* o = part + (size_t)blockIdx.x * 2560;
  o[0 * NSEG + t] = (float)n;
  o[1 * NSEG + t] = s0;   o[2 * NSEG + t] = s1;   o[3 * NSEG + t] = s2;
  o[4 * NSEG + t] = q00;  o[5 * NSEG + t] = q11;  o[6 * NSEG + t] = q22;
  o[7 * NSEG + t] = q01;  o[8 * NSEG + t] = q02;  o[9 * NSEG + t] = q12;
}

// -------- Kernel 1b: sum 128 block-partials per batch (4-chunk split) -----
// 320 blocks: (b, m, chunk c of 32 partials) -> acc[b][c][m][s].
// 8 unrolled rounds of coalesced 1KB lines; k_stats sums the 4 chunks.
__global__ __launch_bounds__(256) void k_reduce(const float* __restrict__ part,
                                                float* __restrict__ acc) {
  const int bm = blockIdx.x >> 2, c = blockIdx.x & 3;
  const int b = bm / 10, m = bm % 10;
  const float* p = part + ((size_t)(b * 128 + c * 32)) * 2560 + m * 256 + threadIdx.x;
  float s0 = 0.f, s1 = 0.f, s2 = 0.f, s3 = 0.f;
  for (int i = 0; i < 32; i += 4) {
    s0 += p[(size_t)(i + 0) * 2560];
    s1 += p[(size_t)(i + 1) * 2560];
    s2 += p[(size_t)(i + 2) * 2560];
    s3 += p[(size_t)(i + 3) * 2560];
  }
  acc[(size_t)((b * 4 + c) * 10 + m) * 256 + threadIdx.x] = (s0 + s1) + (s2 + s3);
}

// -------- Kernel 2: moments -> mean/std -> reduce_conv -> L2 normalize ----
__global__ __launch_bounds__(256) void k_stats(const float* __restrict__ acc,
                                               const float* __restrict__ W_pix,
                                               const float* __restrict__ b_pix,
                                               const float* __restrict__ W_red,
                                               const float* __restrict__ b_red,
                                               float* __restrict__ rn) {
  __shared__ float wred[64 * 129];
  __shared__ float comb[4][132];
  const int t = threadIdx.x;

  for (int j4 = t; j4 < 2048; j4 += 256) {
    const int row = j4 >> 5;
    const int c4  = (j4 & 31) << 2;
    float4 v = ((const float4*)W_red)[j4];
    float* d = &wred[row * 129 + c4];
    d[0] = v.x; d[1] = v.y; d[2] = v.z; d[3] = v.w;
  }
  __syncthreads();

  const int w = t >> 6;
  const int f = t & 63;
  const int seg = blockIdx.x * 4 + w;
  const int b = seg >> 8;
  const int s = seg & 255;

  // sum the 4 chunk-partials per moment (warp-uniform broadcast loads)
  float mm[10];
  #pragma unroll
  for (int m = 0; m < 10; ++m) {
    float v = 0.f;
    #pragma unroll
    for (int c = 0; c < 4; ++c)
      v += acc[(size_t)((b * 4 + c) * 10 + m) * 256 + s];
    mm[m] = v;
  }
  const float N   = fmaxf(mm[0], 1.0f);
  const float S0  = mm[1], S1 = mm[2], S2 = mm[3];
  const float M00 = mm[4], M11 = mm[5], M22 = mm[6];
  const float M01 = mm[7], M02 = mm[8], M12 = mm[9];

  const float w0 = W_pix[f * 3 + 0];
  const float w1 = W_pix[f * 3 + 1];
  const float w2 = W_pix[f * 3 + 2];
  const float bf = b_pix[f];

  const float wS   = w0 * S0 + w1 * S1 + w2 * S2;
  const float mean = (wS + N * bf) / N;
  const float ssq  = w0 * w0 * M00 + w1 * w1 * M11 + w2 * w2 * M22
                   + 2.f * (w0 * w1 * M01 + w0 * w2 * M02 + w1 * w2 * M12)
                   + 2.f * bf * wS + N * bf * bf;
  const float var  = ssq / N - mean * mean;
  const float stdv = sqrtf(fmaxf(var, 1e-6f));

  comb[w][f]      = mean;
  comb[w][64 + f] = stdv;
  __syncthreads();

  float r = b_red[f];
  const float* wr = &wred[f * 129];
  const float* cb = comb[w];
  for (int g = 0; g < 128; ++g) r += wr[g] * cb[g];

  float sq = r * r;
  #pragma unroll
  for (int off = 32; off > 0; off >>= 1) sq += __shfl_xor(sq, off, 64);
  const float inv = 1.0f / fmaxf(sqrtf(sq), 1e-12f);

  rn[(size_t)seg * 64 + f] = r * inv;
}

// -------- Kernel 3: sim = rn rn^T, fused conv1x1 + BN(eval) + ReLU --------
__global__ __launch_bounds__(256) void k_sim(const float* __restrict__ rn,
                                             float* __restrict__ out,
                                             const float* __restrict__ w_sim,
                                             const float* __restrict__ b_sim,
                                             const float* __restrict__ bn_g,
                                             const float* __restrict__ bn_b,
                                             const float* __restrict__ bn_m,
                                             const float* __restrict__ bn_v) {
  __shared__ float A[64 * 65];
  __shared__ float Bt[64 * 65];
  const int t  = threadIdx.x;
  const int b  = blockIdx.x >> 4;
  const int ti = (blockIdx.x >> 2) & 3;
  const int tj = blockIdx.x & 3;

  const float4* rn4 = (const float4*)(rn + (size_t)b * NSEG * 64);
  for (int j4 = t; j4 < 1024; j4 += 256) {
    const int row = j4 >> 4;
    const int c4  = (j4 & 15) << 2;
    float4 va = rn4[(ti * 64 + row) * 16 + (j4 & 15)];
    float* da = &A[row * 65 + c4];
    da[0] = va.x; da[1] = va.y; da[2] = va.z; da[3] = va.w;
    float4 vb = rn4[(tj * 64 + row) * 16 + (j4 & 15)];
    float* db = &Bt[row * 65 + c4];
    db[0] = vb.x; db[1] = vb.y; db[2] = vb.z; db[3] = vb.w;
  }
  __syncthreads();

  const int tx = t & 15;
  const int ty = t >> 4;
  float acc[4][4] = {{0.f}};
  for (int k = 0; k < 64; ++k) {
    float av[4], bv[4];
    #pragma unroll
    for (int i = 0; i < 4; ++i) av[i] = A[(ty * 4 + i) * 65 + k];
    #pragma unroll
    for (int j = 0; j < 4; ++j) bv[j] = Bt[(tx * 4 + j) * 65 + k];
    #pragma unroll
    for (int i = 0; i < 4; ++i)
      #pragma unroll
      for (int j = 0; j < 4; ++j) acc[i][j] += av[i] * bv[j];
  }

  const float invsd = 1.0f / sqrtf(bn_v[0] + 1e-5f);
  const float scale = w_sim[0] * bn_g[0] * invsd;
  const float shift = (b_sim[0] - bn_m[0]) * bn_g[0] * invsd + bn_b[0];

  #pragma unroll
  for (int i = 0; i < 4; ++i) {
    float4 v;
    v.x = fmaxf(acc[i][0] * scale + shift, 0.f);
    v.y = fmaxf(acc[i][1] * scale + shift, 0.f);
    v.z = fmaxf(acc[i][2] * scale + shift, 0.f);
    v.w = fmaxf(acc[i][3] * scale + shift, 0.f);
    const int base = b * 65536 + (ti * 64 + ty * 4 + i) * 256 + tj * 64;
    ((float4*)out)[(base >> 2) + tx] = v;
  }
}

extern "C" void kernel_launch(void* const* d_in, const int* in_sizes, int n_in,
                              void* d_out, int out_size, void* d_ws, size_t ws_size,
                              hipStream_t stream) {
  (void)in_sizes; (void)n_in; (void)out_size; (void)ws_size;
  const float* x      = (const float*)d_in[0];
  const int*   labels = (const int*)d_in[1];
  const float* W_pix  = (const float*)d_in[3];
  const float* b_pix  = (const float*)d_in[4];
  const float* W_red  = (const float*)d_in[5];
  const float* b_red  = (const float*)d_in[6];
  const float* w_sim  = (const float*)d_in[7];
  const float* b_sim  = (const float*)d_in[8];
  const float* bn_g   = (const float*)d_in[9];
  const float* bn_b   = (const float*)d_in[10];
  const float* bn_m   = (const float*)d_in[11];
  const float* bn_v   = (const float*)d_in[12];
  float* out = (float*)d_out;

  float* part = (float*)d_ws;                          // 1024*2560 f32 = 10.5 MB
  float* acc  = part + (size_t)1024 * 2560;            // 8*4*10*256 = 320 KB
  float* rn   = acc + NB * 4 * 10 * NSEG;              // 8*256*64 = 512 KB

  k_moments<<<dim3(1024), dim3(256), 0, stream>>>(x, labels, part);
  k_reduce<<<dim3(320), dim3(256), 0, stream>>>(part, acc);
  k_stats<<<dim3(512), dim3(256), 0, stream>>>(acc, W_pix, b_pix, W_red, b_red, rn);
  k_sim<<<dim3(128), dim3(256), 0, stream>>>(rn, out, w_sim, b_sim, bn_g, bn_b, bn_m, bn_v);
}